// Round 9
// baseline (180.145 us; speedup 1.0000x reference)
//
#include <hip/hip_runtime.h>

#define NT     25600   // B*S tokens
#define WCH    16      // chars per token
#define DIM    64
#define VOCAB  96
#define HID    128
#define KP     416     // GEMM K: 52 slot8-groups * 8
#define TOKB   64      // tokens per block in fused kernel
// T2 layout: [13 octets][14 slots][96 chars][8 halves]

typedef __attribute__((ext_vector_type(8))) _Float16 h8;
typedef __attribute__((ext_vector_type(4))) float f32x4;
typedef __attribute__((ext_vector_type(4))) int i32x4;

__device__ __forceinline__ float tanh_fast(float m) {
  float t = fminf(fmaxf(m, -9.f), 9.f);
  float e = __builtin_amdgcn_exp2f(t * 2.885390082f);  // e^{2t}
  return 1.f - 2.f * __builtin_amdgcn_rcpf(e + 1.f);
}

// ================= prep kernel: 3 roles by blockIdx =================
// A [0,168):   T2 build; slot = b/12, char-group = b%12 (8 chars)
// B [168,232): wprojP[128][416] f16 in slot8-major k order
// C [232,488): hw = tw0|gw0|tw1|gw1 as f16, 128*128 each
__global__ __launch_bounds__(256) void k_prep(
    const float* __restrict__ cv,
    const float* __restrict__ f2, const float* __restrict__ f3,
    const float* __restrict__ f4, const float* __restrict__ f5,
    const float* __restrict__ wproj,
    const float* __restrict__ tw0, const float* __restrict__ gw0,
    const float* __restrict__ tw1, const float* __restrict__ gw1,
    _Float16* __restrict__ T2, _Float16* __restrict__ wprojP,
    _Float16* __restrict__ hw) {
  __shared__ float fS[100 * 65];
  __shared__ float cvS[8 * 65];
  const int tid = threadIdx.x;
  const int b = blockIdx.x;

  if (b < 168) {
    const int slot = b / 12, cg = b - slot * 12;
    int wi, j;
    if (slot < 2)      { wi = 0; j = slot; }
    else if (slot < 5) { wi = 1; j = slot - 2; }
    else if (slot < 9) { wi = 2; j = slot - 5; }
    else               { wi = 3; j = slot - 9; }
    const float* filt = (wi == 0) ? f2 : (wi == 1) ? f3 : (wi == 2) ? f4 : f5;
    const int rowlen = (wi + 2) * DIM;
    for (int idx = tid; idx < 100 * DIM; idx += 256) {
      int f = idx >> 6, d = idx & 63;
      fS[f * 65 + d] = filt[f * rowlen + j * DIM + d];
    }
    for (int idx = tid; idx < 8 * DIM; idx += 256) {
      int c = idx >> 6, d = idx & 63;
      cvS[c * 65 + d] = cv[(cg * 8 + c) * DIM + d];
    }
    __syncthreads();
    for (int idx = tid; idx < 8 * 104; idx += 256) {
      int cl = idx / 104, f = idx - cl * 104;
      float s = 0.f;
      if (f < 100) {
#pragma unroll 8
        for (int d = 0; d < DIM; ++d) s += cvS[cl * 65 + d] * fS[f * 65 + d];
      }
      T2[((size_t)(f >> 3) * 14 + slot) * 768 + (cg * 8 + cl) * 8 + (f & 7)] =
          (_Float16)s;
    }
  } else if (b < 232) {
    const int n = (b - 168) * 2 + (tid >> 7);
    for (int k = tid & 127; k < KP; k += 128) {
      int s8 = k >> 3;
      int wi = s8 / 13;
      int fl = (s8 - wi * 13) * 8 + (k & 7);
      wprojP[n * KP + k] =
          (fl < 100) ? (_Float16)wproj[n * 400 + wi * 100 + fl] : (_Float16)0.f;
    }
  } else {
    const int idx = (b - 232) * 256 + tid;   // < 65536
    const int which = idx >> 14, r = idx & 16383;
    const float* src = (which == 0) ? tw0 : (which == 1) ? gw0
                     : (which == 2) ? tw1 : gw1;
    hw[idx] = (_Float16)src[r];
  }
}

// ---------------- conv for one (token=lane, window, octet), global gather ----------------
// T2 slice addressing: ((o*14 + slot)*96 + char)*8 halves; ch[] pre-scaled by 8.
// A wave's 64 addresses span 96*16B = 1.5 KB (~12 cache lines) -> low L1 divergence.
template<int WI>
__device__ __forceinline__ void conv_g(const _Float16* __restrict__ T2,
                                       const int* __restrict__ ch,
                                       _Float16* __restrict__ convA,
                                       int lane, int o) {
  constexpr int W = WI + 2, L = 15 - WI;
  constexpr int SB = (WI == 0) ? 0 : (WI == 1) ? 2 : (WI == 2) ? 5 : 9;
  const _Float16* Tb = T2 + ((size_t)o * 14 + SB) * 768;
  h8 m;
  {
    h8 s = *(const h8*)(Tb + ch[0]);
#pragma unroll
    for (int j = 1; j < W; ++j) s += *(const h8*)(Tb + j * 768 + ch[j]);
    m = s;
  }
#pragma unroll
  for (int l = 1; l < L; ++l) {
    h8 s = *(const h8*)(Tb + ch[l]);
#pragma unroll
    for (int j = 1; j < W; ++j) s += *(const h8*)(Tb + j * 768 + ch[l + j]);
    m = __builtin_elementwise_max(m, s);
  }
  h8 r;
#pragma unroll
  for (int i = 0; i < 8; ++i) r[i] = (_Float16)tanh_fast((float)m[i]);
  const int s8 = WI * 13 + o;
  *(h8*)(convA + (s8 * 64 + lane) * 8) = r;
}

// ================= fused conv (direct L1/L2 gather) + MFMA head =================
// 64 tokens/block, 512 threads (8 waves), token = lane. Each wave owns a
// statically balanced list of (window, octet) units (261-308 wave-loads each);
// no barriers inside conv. Wave w is n-tile w in the GEMMs (hc = w*16+m16).
// A-frag (16x16x32 f16): A[m=lane&15][k=quad*8+j]; D: row=quad*4+reg, col=lane&15.
__global__ __launch_bounds__(512) void k_fused(
    const int* __restrict__ chars,
    const _Float16* __restrict__ T2,
    const _Float16* __restrict__ wprojP,
    const _Float16* __restrict__ hw,
    const float* __restrict__ tb0, const float* __restrict__ tb1,
    const float* __restrict__ gb0, const float* __restrict__ gb1,
    float* __restrict__ out) {
  __shared__ __align__(16) char lds[53248];
  _Float16* convA = (_Float16*)lds;   // 52 groups x 64 tokens x 8 halves = 53,248 B
  _Float16* xA    = (_Float16*)lds;   // 16 KB alias (post-GEMM, after barrier)

  const int tid = threadIdx.x;
  const int wave = tid >> 6, lane = tid & 63;
  const int m16 = lane & 15, quad = lane >> 4;
  const int tok0 = blockIdx.x * TOKB;
  const f32x4 zero = {0.f, 0.f, 0.f, 0.f};

  // per-thread chars for token = lane (each wave loads its own copy), scaled by 8
  int ch[WCH];
  {
    const i32x4* cp = (const i32x4*)(chars + (size_t)(tok0 + lane) * WCH);
#pragma unroll
    for (int q = 0; q < 4; ++q) {
      i32x4 v = cp[q];
#pragma unroll
      for (int i = 0; i < 4; ++i) ch[q * 4 + i] = v[i] * 8;
    }
  }

  // ---- conv: statically balanced (window, octet) units per wave ----
  switch (wave) {
    case 0: for (int o = 0;  o < 5;  ++o) conv_g<3>(T2, ch, convA, lane, o); break;
    case 1: for (int o = 5;  o < 10; ++o) conv_g<3>(T2, ch, convA, lane, o); break;
    case 2: for (int o = 10; o < 13; ++o) conv_g<3>(T2, ch, convA, lane, o);
            for (int o = 0;  o < 2;  ++o) conv_g<2>(T2, ch, convA, lane, o); break;
    case 3: for (int o = 2;  o < 8;  ++o) conv_g<2>(T2, ch, convA, lane, o); break;
    case 4: for (int o = 8;  o < 13; ++o) conv_g<2>(T2, ch, convA, lane, o);
            conv_g<0>(T2, ch, convA, lane, 0); break;
    case 5: for (int o = 0;  o < 7;  ++o) conv_g<1>(T2, ch, convA, lane, o); break;
    case 6: for (int o = 7;  o < 13; ++o) conv_g<1>(T2, ch, convA, lane, o);
            conv_g<0>(T2, ch, convA, lane, 1); break;
    default: for (int o = 2; o < 13; ++o) conv_g<0>(T2, ch, convA, lane, o); break;
  }
  __syncthreads();

  // ---- projection GEMM: xp = conv @ wprojP^T, K=416; wave = n-tile ----
  const int hc = wave * 16 + m16;
  f32x4 xp[4];
#pragma unroll
  for (int mt = 0; mt < 4; ++mt) xp[mt] = zero;

  for (int ks = 0; ks < 13; ++ks) {
    const int s8 = ks * 4 + quad;
    h8 b = *(const h8*)(wprojP + (size_t)hc * KP + s8 * 8);
#pragma unroll
    for (int mt = 0; mt < 4; ++mt) {
      h8 a = *(const h8*)(convA + (s8 * 64 + mt * 16 + m16) * 8);
      xp[mt] = __builtin_amdgcn_mfma_f32_16x16x32_f16(a, b, xp[mt], 0, 0, 0);
    }
  }
  __syncthreads();   // all convA reads done before xA alias writes

  // write x0 (f16) into xA [hid>>3][64 rows][8]
#pragma unroll
  for (int mt = 0; mt < 4; ++mt)
#pragma unroll
    for (int r = 0; r < 4; ++r)
      xA[(hc >> 3) * 512 + (mt * 16 + quad * 4 + r) * 8 + (hc & 7)] =
          (_Float16)xp[mt][r];
  __syncthreads();

  // ---- highway layers ----
#pragma unroll
  for (int layer = 0; layer < 2; ++layer) {
    const _Float16* tw = hw + (layer ? 2 : 0) * HID * HID;
    const _Float16* gw = hw + (layer ? 3 : 1) * HID * HID;
    const float* tbv = layer ? tb1 : tb0;
    const float* gbv = layer ? gb1 : gb0;
    float bt = tbv[hc], bg = gbv[hc];

    f32x4 at[4], ag[4];
#pragma unroll
    for (int mt = 0; mt < 4; ++mt) { at[mt] = zero; ag[mt] = zero; }

#pragma unroll
    for (int ks = 0; ks < 4; ++ks) {
      const int ko = ks * 32 + quad * 8;
      h8 btw = *(const h8*)(tw + (size_t)hc * HID + ko);
      h8 bgw = *(const h8*)(gw + (size_t)hc * HID + ko);
#pragma unroll
      for (int mt = 0; mt < 4; ++mt) {
        h8 a = *(const h8*)(xA + (ks * 4 + quad) * 512 + (mt * 16 + m16) * 8);
        at[mt] = __builtin_amdgcn_mfma_f32_16x16x32_f16(a, btw, at[mt], 0, 0, 0);
        ag[mt] = __builtin_amdgcn_mfma_f32_16x16x32_f16(a, bgw, ag[mt], 0, 0, 0);
      }
    }
    __syncthreads();   // xA reads done before overwrite

#pragma unroll
    for (int mt = 0; mt < 4; ++mt)
#pragma unroll
      for (int r = 0; r < 4; ++r) {
        float g = 1.f / (1.f + __builtin_amdgcn_exp2f(
                             -(ag[mt][r] + bg) * 1.442695041f));
        float tt = fmaxf(at[mt][r] + bt, 0.f);
        float xn = g * tt + (1.f - g) * xp[mt][r];
        xp[mt][r] = xn;
        int row = mt * 16 + quad * 4 + r;
        if (layer == 0)
          xA[(hc >> 3) * 512 + row * 8 + (hc & 7)] = (_Float16)xn;
        else
          out[(size_t)(tok0 + row) * HID + hc] = xn;
      }
    if (layer == 0) __syncthreads();
  }
}

extern "C" void kernel_launch(void* const* d_in, const int* in_sizes, int n_in,
                              void* d_out, int out_size, void* d_ws, size_t ws_size,
                              hipStream_t stream) {
  (void)in_sizes; (void)n_in; (void)out_size; (void)ws_size;
  const int* chars = (const int*)d_in[0];
  const float* cv  = (const float*)d_in[1];
  const float* f2  = (const float*)d_in[2];
  const float* f3  = (const float*)d_in[3];
  const float* f4  = (const float*)d_in[4];
  const float* f5  = (const float*)d_in[5];
  const float* wpj = (const float*)d_in[6];
  const float* tw0 = (const float*)d_in[7];
  const float* tb0 = (const float*)d_in[8];
  const float* tw1 = (const float*)d_in[9];
  const float* tb1 = (const float*)d_in[10];
  const float* gw0 = (const float*)d_in[11];
  const float* gb0 = (const float*)d_in[12];
  const float* gw1 = (const float*)d_in[13];
  const float* gb1 = (const float*)d_in[14];
  float* out = (float*)d_out;

  char* ws = (char*)d_ws;
  _Float16* T2     = (_Float16*)ws;                       // 13*14*96*8*2 = 279,552 B
  _Float16* wprojP = (_Float16*)(ws + 279552);            // 106,496 B
  _Float16* hw     = (_Float16*)(ws + 279552 + 106496);   // 131,072 B (total 517,120 B)

  k_prep<<<488, 256, 0, stream>>>(cv, f2, f3, f4, f5, wpj, tw0, gw0, tw1, gw1,
                                  T2, wprojP, hw);
  k_fused<<<NT / TOKB, 512, 0, stream>>>(chars, T2, wprojP, hw,
                                         tb0, tb1, gb0, gb1, out);
}

// Round 10
// 152.104 us; speedup vs baseline: 1.1843x; 1.1843x over previous
//
#include <hip/hip_runtime.h>

#define NT     25600   // B*S tokens
#define WCH    16      // chars per token
#define DIM    64
#define VOCAB  96
#define HID    128
#define KP     416     // GEMM K: 52 slot8-groups * 8
#define TOKB   64      // tokens per block in head kernel
#define SLOT   9984    // halves per T3 slot (96 chars x 104 feats)
// T3 layout: [14 slots][96 chars][104 feats] f16 (feats 100..103 = 0)
// convG layout: [52 s8-groups][25600 tokens][8 halves]

typedef __attribute__((ext_vector_type(8))) _Float16 h8;
typedef __attribute__((ext_vector_type(4))) float f32x4;
typedef __attribute__((ext_vector_type(4))) int i32x4;

__device__ __forceinline__ float tanh_fast(float m) {
  float t = fminf(fmaxf(m, -9.f), 9.f);
  float e = __builtin_amdgcn_exp2f(t * 2.885390082f);  // e^{2t}
  return 1.f - 2.f * __builtin_amdgcn_rcpf(e + 1.f);
}

// ================= prep kernel: 3 roles by blockIdx =================
// A [0,168):   T3 build; slot = b/12, char-group = b%12 (8 chars)
// B [168,232): wprojP[128][416] f16 in slot8-major k order
// C [232,488): hw = tw0|gw0|tw1|gw1 as f16, 128*128 each
__global__ __launch_bounds__(256) void k_prep(
    const float* __restrict__ cv,
    const float* __restrict__ f2, const float* __restrict__ f3,
    const float* __restrict__ f4, const float* __restrict__ f5,
    const float* __restrict__ wproj,
    const float* __restrict__ tw0, const float* __restrict__ gw0,
    const float* __restrict__ tw1, const float* __restrict__ gw1,
    _Float16* __restrict__ T3, _Float16* __restrict__ wprojP,
    _Float16* __restrict__ hw) {
  __shared__ float fS[100 * 65];
  __shared__ float cvS[8 * 65];
  const int tid = threadIdx.x;
  const int b = blockIdx.x;

  if (b < 168) {
    const int slot = b / 12, cg = b - slot * 12;
    int wi, j;
    if (slot < 2)      { wi = 0; j = slot; }
    else if (slot < 5) { wi = 1; j = slot - 2; }
    else if (slot < 9) { wi = 2; j = slot - 5; }
    else               { wi = 3; j = slot - 9; }
    const float* filt = (wi == 0) ? f2 : (wi == 1) ? f3 : (wi == 2) ? f4 : f5;
    const int rowlen = (wi + 2) * DIM;
    for (int idx = tid; idx < 100 * DIM; idx += 256) {
      int f = idx >> 6, d = idx & 63;
      fS[f * 65 + d] = filt[f * rowlen + j * DIM + d];
    }
    for (int idx = tid; idx < 8 * DIM; idx += 256) {
      int c = idx >> 6, d = idx & 63;
      cvS[c * 65 + d] = cv[(cg * 8 + c) * DIM + d];
    }
    __syncthreads();
    for (int idx = tid; idx < 8 * 104; idx += 256) {
      int cl = idx / 104, f = idx - cl * 104;
      float s = 0.f;
      if (f < 100) {
#pragma unroll 8
        for (int d = 0; d < DIM; ++d) s += cvS[cl * 65 + d] * fS[f * 65 + d];
      }
      T3[((size_t)slot * 96 + cg * 8 + cl) * 104 + f] = (_Float16)s;
    }
  } else if (b < 232) {
    const int n = (b - 168) * 2 + (tid >> 7);
    for (int k = tid & 127; k < KP; k += 128) {
      int s8 = k >> 3;
      int wi = s8 / 13;
      int fl = (s8 - wi * 13) * 8 + (k & 7);
      wprojP[n * KP + k] =
          (fl < 100) ? (_Float16)wproj[n * 400 + wi * 100 + fl] : (_Float16)0.f;
    }
  } else {
    const int idx = (b - 232) * 256 + tid;   // < 65536
    const int which = idx >> 14, r = idx & 16383;
    const float* src = (which == 0) ? tw0 : (which == 1) ? gw0
                     : (which == 2) ? tw1 : gw1;
    hw[idx] = (_Float16)src[r];
  }
}

// ================= conv kernel: window-specialized, LDS-resident table =================
// Block segments: [0,100) w=2 (256 tok/blk), [100,260) w=3 (160), [260,420) w=4 (160),
// [420,620) w=5 (128). Stage T3 slots [SB,SB+W) once; then barrier-free LDS gathers.
template<int WI>
__device__ __forceinline__ void conv_block(const int* __restrict__ chars,
                                           const _Float16* __restrict__ Ts,
                                           _Float16* __restrict__ convG,
                                           int t0, int TC) {
  constexpr int W = WI + 2, L = 15 - WI;
  const int nit = TC * 13;
  for (int it = threadIdx.x; it < nit; it += 512) {
    const int oct = it / TC, tloc = it - oct * TC;
    const int token = t0 + tloc;
    int ch[WCH];
    {
      const i32x4* cp = (const i32x4*)(chars + (size_t)token * WCH);
#pragma unroll
      for (int q = 0; q < 4; ++q) {
        i32x4 v = cp[q];
#pragma unroll
        for (int i = 0; i < 4; ++i) ch[q * 4 + i] = v[i] * 104;
      }
    }
    const _Float16* Tb = Ts + oct * 8;
    h8 m;
    {
      h8 s = *(const h8*)(Tb + ch[0]);
#pragma unroll
      for (int j = 1; j < W; ++j) s += *(const h8*)(Tb + j * SLOT + ch[j]);
      m = s;
    }
#pragma unroll
    for (int l = 1; l < L; ++l) {
      h8 s = *(const h8*)(Tb + ch[l]);
#pragma unroll
      for (int j = 1; j < W; ++j) s += *(const h8*)(Tb + j * SLOT + ch[l + j]);
      m = __builtin_elementwise_max(m, s);
    }
    h8 r;
#pragma unroll
    for (int i = 0; i < 8; ++i) r[i] = (_Float16)tanh_fast((float)m[i]);
    const int s8 = WI * 13 + oct;
    *(h8*)(convG + ((size_t)s8 * NT + token) * 8) = r;
  }
}

__global__ __launch_bounds__(512) void k_conv(const int* __restrict__ chars,
                                              const _Float16* __restrict__ T3,
                                              _Float16* __restrict__ convG) {
  __shared__ __align__(16) _Float16 Ts[5 * SLOT];   // 99,840 B max (w=5)
  const int b = blockIdx.x;
  int wi, b0, TC;
  if (b < 100)      { wi = 0; b0 = 0;   TC = 256; }
  else if (b < 260) { wi = 1; b0 = 100; TC = 160; }
  else if (b < 420) { wi = 2; b0 = 260; TC = 160; }
  else              { wi = 3; b0 = 420; TC = 128; }
  const int W = wi + 2;
  const int SB = (wi == 0) ? 0 : (wi == 1) ? 2 : (wi == 2) ? 5 : 9;
  const int t0 = (b - b0) * TC;

  // stage T3 slots [SB, SB+W): contiguous, coalesced, conflict-free
  const _Float16* src = T3 + (size_t)SB * SLOT;
  const int nchunk = W * (SLOT / 8);
  for (int r = threadIdx.x; r < nchunk; r += 512)
    *(h8*)(Ts + r * 8) = *(const h8*)(src + r * 8);
  __syncthreads();

  switch (wi) {
    case 0: conv_block<0>(chars, Ts, convG, t0, TC); break;
    case 1: conv_block<1>(chars, Ts, convG, t0, TC); break;
    case 2: conv_block<2>(chars, Ts, convG, t0, TC); break;
    default: conv_block<3>(chars, Ts, convG, t0, TC); break;
  }
}

// ================= head kernel: MFMA proj + 2 highway layers =================
// 64 tokens/block, 512 threads (8 waves); wave = n-tile (hc = wave*16+m16).
// A-frag (16x16x32 f16): A[m=lane&15][k=quad*8+j]; D: row=quad*4+reg, col=lane&15.
__global__ __launch_bounds__(512) void k_head(
    const _Float16* __restrict__ convG,
    const _Float16* __restrict__ wprojP,
    const _Float16* __restrict__ hw,
    const float* __restrict__ tb0, const float* __restrict__ tb1,
    const float* __restrict__ gb0, const float* __restrict__ gb1,
    float* __restrict__ out) {
  __shared__ __align__(16) char lds[53248];
  _Float16* convA = (_Float16*)lds;   // 52 x 64 x 8 halves
  _Float16* xA    = (_Float16*)lds;   // 16 KB alias (post-GEMM)

  const int tid = threadIdx.x;
  const int wave = tid >> 6, lane = tid & 63;
  const int m16 = lane & 15, quad = lane >> 4;
  const int tok0 = blockIdx.x * TOKB;
  const f32x4 zero = {0.f, 0.f, 0.f, 0.f};

  // stage convA: coalesced global reads, linear LDS writes
  for (int g = wave; g < 52; g += 8) {
    h8 v = *(const h8*)(convG + ((size_t)g * NT + tok0 + lane) * 8);
    *(h8*)(convA + (g * 64 + lane) * 8) = v;
  }
  __syncthreads();

  // ---- projection GEMM: xp = conv @ wprojP^T, K=416; wave = n-tile ----
  const int hc = wave * 16 + m16;
  f32x4 xp[4];
#pragma unroll
  for (int mt = 0; mt < 4; ++mt) xp[mt] = zero;

  for (int ks = 0; ks < 13; ++ks) {
    const int s8 = ks * 4 + quad;
    h8 b = *(const h8*)(wprojP + (size_t)hc * KP + s8 * 8);
#pragma unroll
    for (int mt = 0; mt < 4; ++mt) {
      h8 a = *(const h8*)(convA + (s8 * 64 + mt * 16 + m16) * 8);
      xp[mt] = __builtin_amdgcn_mfma_f32_16x16x32_f16(a, b, xp[mt], 0, 0, 0);
    }
  }
  __syncthreads();   // all convA reads done before xA alias writes

#pragma unroll
  for (int mt = 0; mt < 4; ++mt)
#pragma unroll
    for (int r = 0; r < 4; ++r)
      xA[(hc >> 3) * 512 + (mt * 16 + quad * 4 + r) * 8 + (hc & 7)] =
          (_Float16)xp[mt][r];
  __syncthreads();

#pragma unroll
  for (int layer = 0; layer < 2; ++layer) {
    const _Float16* tw = hw + (layer ? 2 : 0) * HID * HID;
    const _Float16* gw = hw + (layer ? 3 : 1) * HID * HID;
    const float* tbv = layer ? tb1 : tb0;
    const float* gbv = layer ? gb1 : gb0;
    float bt = tbv[hc], bg = gbv[hc];

    f32x4 at[4], ag[4];
#pragma unroll
    for (int mt = 0; mt < 4; ++mt) { at[mt] = zero; ag[mt] = zero; }

#pragma unroll
    for (int ks = 0; ks < 4; ++ks) {
      const int ko = ks * 32 + quad * 8;
      h8 btw = *(const h8*)(tw + (size_t)hc * HID + ko);
      h8 bgw = *(const h8*)(gw + (size_t)hc * HID + ko);
#pragma unroll
      for (int mt = 0; mt < 4; ++mt) {
        h8 a = *(const h8*)(xA + (ks * 4 + quad) * 512 + (mt * 16 + m16) * 8);
        at[mt] = __builtin_amdgcn_mfma_f32_16x16x32_f16(a, btw, at[mt], 0, 0, 0);
        ag[mt] = __builtin_amdgcn_mfma_f32_16x16x32_f16(a, bgw, ag[mt], 0, 0, 0);
      }
    }
    __syncthreads();

#pragma unroll
    for (int mt = 0; mt < 4; ++mt)
#pragma unroll
      for (int r = 0; r < 4; ++r) {
        float g = 1.f / (1.f + __builtin_amdgcn_exp2f(
                             -(ag[mt][r] + bg) * 1.442695041f));
        float tt = fmaxf(at[mt][r] + bt, 0.f);
        float xn = g * tt + (1.f - g) * xp[mt][r];
        xp[mt][r] = xn;
        int row = mt * 16 + quad * 4 + r;
        if (layer == 0)
          xA[(hc >> 3) * 512 + row * 8 + (hc & 7)] = (_Float16)xn;
        else
          out[(size_t)(tok0 + row) * HID + hc] = xn;
      }
    if (layer == 0) __syncthreads();
  }
}

// ================= fallback fused kernel (round-9 structure, T3 layout) =================
template<int WI>
__device__ __forceinline__ void conv_g(const _Float16* __restrict__ T3,
                                       const int* __restrict__ ch,
                                       _Float16* __restrict__ convA,
                                       int lane, int o) {
  constexpr int W = WI + 2, L = 15 - WI;
  constexpr int SB = (WI == 0) ? 0 : (WI == 1) ? 2 : (WI == 2) ? 5 : 9;
  const _Float16* Tb = T3 + (size_t)SB * SLOT + o * 8;
  h8 m;
  {
    h8 s = *(const h8*)(Tb + ch[0]);
#pragma unroll
    for (int j = 1; j < W; ++j) s += *(const h8*)(Tb + j * SLOT + ch[j]);
    m = s;
  }
#pragma unroll
  for (int l = 1; l < L; ++l) {
    h8 s = *(const h8*)(Tb + ch[l]);
#pragma unroll
    for (int j = 1; j < W; ++j) s += *(const h8*)(Tb + j * SLOT + ch[l + j]);
    m = __builtin_elementwise_max(m, s);
  }
  h8 r;
#pragma unroll
  for (int i = 0; i < 8; ++i) r[i] = (_Float16)tanh_fast((float)m[i]);
  const int s8 = WI * 13 + o;
  *(h8*)(convA + (s8 * 64 + lane) * 8) = r;
}

__global__ __launch_bounds__(512) void k_fb(
    const int* __restrict__ chars,
    const _Float16* __restrict__ T3,
    const _Float16* __restrict__ wprojP,
    const _Float16* __restrict__ hw,
    const float* __restrict__ tb0, const float* __restrict__ tb1,
    const float* __restrict__ gb0, const float* __restrict__ gb1,
    float* __restrict__ out) {
  __shared__ __align__(16) char lds[53248];
  _Float16* convA = (_Float16*)lds;
  _Float16* xA    = (_Float16*)lds;

  const int tid = threadIdx.x;
  const int wave = tid >> 6, lane = tid & 63;
  const int m16 = lane & 15, quad = lane >> 4;
  const int tok0 = blockIdx.x * TOKB;
  const f32x4 zero = {0.f, 0.f, 0.f, 0.f};

  int ch[WCH];
  {
    const i32x4* cp = (const i32x4*)(chars + (size_t)(tok0 + lane) * WCH);
#pragma unroll
    for (int q = 0; q < 4; ++q) {
      i32x4 v = cp[q];
#pragma unroll
      for (int i = 0; i < 4; ++i) ch[q * 4 + i] = v[i] * 104;
    }
  }

  switch (wave) {
    case 0: for (int o = 0;  o < 5;  ++o) conv_g<3>(T3, ch, convA, lane, o); break;
    case 1: for (int o = 5;  o < 10; ++o) conv_g<3>(T3, ch, convA, lane, o); break;
    case 2: for (int o = 10; o < 13; ++o) conv_g<3>(T3, ch, convA, lane, o);
            for (int o = 0;  o < 2;  ++o) conv_g<2>(T3, ch, convA, lane, o); break;
    case 3: for (int o = 2;  o < 8;  ++o) conv_g<2>(T3, ch, convA, lane, o); break;
    case 4: for (int o = 8;  o < 13; ++o) conv_g<2>(T3, ch, convA, lane, o);
            conv_g<0>(T3, ch, convA, lane, 0); break;
    case 5: for (int o = 0;  o < 7;  ++o) conv_g<1>(T3, ch, convA, lane, o); break;
    case 6: for (int o = 7;  o < 13; ++o) conv_g<1>(T3, ch, convA, lane, o);
            conv_g<0>(T3, ch, convA, lane, 1); break;
    default: for (int o = 2; o < 13; ++o) conv_g<0>(T3, ch, convA, lane, o); break;
  }
  __syncthreads();

  const int hc = wave * 16 + m16;
  f32x4 xp[4];
#pragma unroll
  for (int mt = 0; mt < 4; ++mt) xp[mt] = zero;
  for (int ks = 0; ks < 13; ++ks) {
    const int s8 = ks * 4 + quad;
    h8 b = *(const h8*)(wprojP + (size_t)hc * KP + s8 * 8);
#pragma unroll
    for (int mt = 0; mt < 4; ++mt) {
      h8 a = *(const h8*)(convA + (s8 * 64 + mt * 16 + m16) * 8);
      xp[mt] = __builtin_amdgcn_mfma_f32_16x16x32_f16(a, b, xp[mt], 0, 0, 0);
    }
  }
  __syncthreads();
#pragma unroll
  for (int mt = 0; mt < 4; ++mt)
#pragma unroll
    for (int r = 0; r < 4; ++r)
      xA[(hc >> 3) * 512 + (mt * 16 + quad * 4 + r) * 8 + (hc & 7)] =
          (_Float16)xp[mt][r];
  __syncthreads();
#pragma unroll
  for (int layer = 0; layer < 2; ++layer) {
    const _Float16* tw = hw + (layer ? 2 : 0) * HID * HID;
    const _Float16* gw = hw + (layer ? 3 : 1) * HID * HID;
    const float* tbv = layer ? tb1 : tb0;
    const float* gbv = layer ? gb1 : gb0;
    float bt = tbv[hc], bg = gbv[hc];
    f32x4 at[4], ag[4];
#pragma unroll
    for (int mt = 0; mt < 4; ++mt) { at[mt] = zero; ag[mt] = zero; }
#pragma unroll
    for (int ks = 0; ks < 4; ++ks) {
      const int ko = ks * 32 + quad * 8;
      h8 btw = *(const h8*)(tw + (size_t)hc * HID + ko);
      h8 bgw = *(const h8*)(gw + (size_t)hc * HID + ko);
#pragma unroll
      for (int mt = 0; mt < 4; ++mt) {
        h8 a = *(const h8*)(xA + (ks * 4 + quad) * 512 + (mt * 16 + m16) * 8);
        at[mt] = __builtin_amdgcn_mfma_f32_16x16x32_f16(a, btw, at[mt], 0, 0, 0);
        ag[mt] = __builtin_amdgcn_mfma_f32_16x16x32_f16(a, bgw, ag[mt], 0, 0, 0);
      }
    }
    __syncthreads();
#pragma unroll
    for (int mt = 0; mt < 4; ++mt)
#pragma unroll
      for (int r = 0; r < 4; ++r) {
        float g = 1.f / (1.f + __builtin_amdgcn_exp2f(
                             -(ag[mt][r] + bg) * 1.442695041f));
        float tt = fmaxf(at[mt][r] + bt, 0.f);
        float xn = g * tt + (1.f - g) * xp[mt][r];
        xp[mt][r] = xn;
        int row = mt * 16 + quad * 4 + r;
        if (layer == 0)
          xA[(hc >> 3) * 512 + row * 8 + (hc & 7)] = (_Float16)xn;
        else
          out[(size_t)(tok0 + row) * HID + hc] = xn;
      }
    if (layer == 0) __syncthreads();
  }
}

extern "C" void kernel_launch(void* const* d_in, const int* in_sizes, int n_in,
                              void* d_out, int out_size, void* d_ws, size_t ws_size,
                              hipStream_t stream) {
  (void)in_sizes; (void)n_in; (void)out_size;
  const int* chars = (const int*)d_in[0];
  const float* cv  = (const float*)d_in[1];
  const float* f2  = (const float*)d_in[2];
  const float* f3  = (const float*)d_in[3];
  const float* f4  = (const float*)d_in[4];
  const float* f5  = (const float*)d_in[5];
  const float* wpj = (const float*)d_in[6];
  const float* tw0 = (const float*)d_in[7];
  const float* tb0 = (const float*)d_in[8];
  const float* tw1 = (const float*)d_in[9];
  const float* tb1 = (const float*)d_in[10];
  const float* gw0 = (const float*)d_in[11];
  const float* gb0 = (const float*)d_in[12];
  const float* gw1 = (const float*)d_in[13];
  const float* gb1 = (const float*)d_in[14];
  float* out = (float*)d_out;

  char* ws = (char*)d_ws;
  _Float16* T3     = (_Float16*)ws;                       // 279,552 B
  _Float16* wprojP = (_Float16*)(ws + 279552);            // 106,496 B
  _Float16* hw     = (_Float16*)(ws + 386048);            // 131,072 B
  _Float16* convG  = (_Float16*)(ws + 517120);            // 21,299,200 B

  k_prep<<<488, 256, 0, stream>>>(cv, f2, f3, f4, f5, wpj, tw0, gw0, tw1, gw1,
                                  T3, wprojP, hw);
  if (ws_size >= (size_t)21816320) {
    k_conv<<<620, 512, 0, stream>>>(chars, T3, convG);
    k_head<<<NT / TOKB, 512, 0, stream>>>(convG, wprojP, hw,
                                          tb0, tb1, gb0, gb1, out);
  } else {
    k_fb<<<NT / TOKB, 512, 0, stream>>>(chars, T3, wprojP, hw,
                                        tb0, tb1, gb0, gb1, out);
  }
}

// Round 11
// 147.066 us; speedup vs baseline: 1.2249x; 1.0343x over previous
//
#include <hip/hip_runtime.h>

#define NT     25600   // B*S tokens
#define WCH    16      // chars per token
#define DIM    64
#define VOCAB  96
#define HID    128
#define KP     416     // GEMM K: 52 slot8-groups * 8
#define TOKB   64      // tokens per block in head kernel
#define SLOT   9984    // halves per T3 slot (96 chars x 104 feats)
// T3 layout: [14 slots][96 chars][104 feats] f16 (feats 100..103 = 0)
// convG layout: [52 s8-groups][25600 tokens][8 halves]

typedef __attribute__((ext_vector_type(8))) _Float16 h8;
typedef __attribute__((ext_vector_type(4))) float f32x4;
typedef __attribute__((ext_vector_type(4))) int i32x4;

__device__ __forceinline__ float tanh_fast(float m) {
  float t = fminf(fmaxf(m, -9.f), 9.f);
  float e = __builtin_amdgcn_exp2f(t * 2.885390082f);  // e^{2t}
  return 1.f - 2.f * __builtin_amdgcn_rcpf(e + 1.f);
}

// ================= prep kernel: 3 roles by blockIdx =================
__global__ __launch_bounds__(256) void k_prep(
    const float* __restrict__ cv,
    const float* __restrict__ f2, const float* __restrict__ f3,
    const float* __restrict__ f4, const float* __restrict__ f5,
    const float* __restrict__ wproj,
    const float* __restrict__ tw0, const float* __restrict__ gw0,
    const float* __restrict__ tw1, const float* __restrict__ gw1,
    _Float16* __restrict__ T3, _Float16* __restrict__ wprojP,
    _Float16* __restrict__ hw) {
  __shared__ float fS[100 * 65];
  __shared__ float cvS[8 * 65];
  const int tid = threadIdx.x;
  const int b = blockIdx.x;

  if (b < 168) {
    const int slot = b / 12, cg = b - slot * 12;
    int wi, j;
    if (slot < 2)      { wi = 0; j = slot; }
    else if (slot < 5) { wi = 1; j = slot - 2; }
    else if (slot < 9) { wi = 2; j = slot - 5; }
    else               { wi = 3; j = slot - 9; }
    const float* filt = (wi == 0) ? f2 : (wi == 1) ? f3 : (wi == 2) ? f4 : f5;
    const int rowlen = (wi + 2) * DIM;
    for (int idx = tid; idx < 100 * DIM; idx += 256) {
      int f = idx >> 6, d = idx & 63;
      fS[f * 65 + d] = filt[f * rowlen + j * DIM + d];
    }
    for (int idx = tid; idx < 8 * DIM; idx += 256) {
      int c = idx >> 6, d = idx & 63;
      cvS[c * 65 + d] = cv[(cg * 8 + c) * DIM + d];
    }
    __syncthreads();
    for (int idx = tid; idx < 8 * 104; idx += 256) {
      int cl = idx / 104, f = idx - cl * 104;
      float s = 0.f;
      if (f < 100) {
#pragma unroll 8
        for (int d = 0; d < DIM; ++d) s += cvS[cl * 65 + d] * fS[f * 65 + d];
      }
      T3[((size_t)slot * 96 + cg * 8 + cl) * 104 + f] = (_Float16)s;
    }
  } else if (b < 232) {
    const int n = (b - 168) * 2 + (tid >> 7);
    for (int k = tid & 127; k < KP; k += 128) {
      int s8 = k >> 3;
      int wi = s8 / 13;
      int fl = (s8 - wi * 13) * 8 + (k & 7);
      wprojP[n * KP + k] =
          (fl < 100) ? (_Float16)wproj[n * 400 + wi * 100 + fl] : (_Float16)0.f;
    }
  } else {
    const int idx = (b - 232) * 256 + tid;   // < 65536
    const int which = idx >> 14, r = idx & 16383;
    const float* src = (which == 0) ? tw0 : (which == 1) ? gw0
                     : (which == 2) ? tw1 : gw1;
    hw[idx] = (_Float16)src[r];
  }
}

// ================= conv kernel: 256 balanced blocks x 1024 threads =================
// Block classes (work-balanced, ~240K lane-gathers each):
//  [0,84)    w=5  TC=305      [84,156)  w=4  TC=356
//  [156,214) w=3  TC=442      [214,256) w=2  TC=610
template<int WI>
__device__ __forceinline__ void conv_block(const int* __restrict__ chars,
                                           const _Float16* __restrict__ Ts,
                                           _Float16* __restrict__ convG,
                                           int t0, int TC) {
  constexpr int W = WI + 2, L = 15 - WI;
  const int nit = TC * 13;
  for (int it = threadIdx.x; it < nit; it += 1024) {
    const int oct = it / TC, tloc = it - oct * TC;
    const int token = t0 + tloc;
    if (token >= NT) continue;
    int ch[WCH];
    {
      const i32x4* cp = (const i32x4*)(chars + (size_t)token * WCH);
#pragma unroll
      for (int q = 0; q < 4; ++q) {
        i32x4 v = cp[q];
#pragma unroll
        for (int i = 0; i < 4; ++i) ch[q * 4 + i] = v[i] * 104;
      }
    }
    const _Float16* Tb = Ts + oct * 8;
    h8 m;
    {
      h8 s = *(const h8*)(Tb + ch[0]);
#pragma unroll
      for (int j = 1; j < W; ++j) s += *(const h8*)(Tb + j * SLOT + ch[j]);
      m = s;
    }
#pragma unroll
    for (int l = 1; l < L; ++l) {
      h8 s = *(const h8*)(Tb + ch[l]);
#pragma unroll
      for (int j = 1; j < W; ++j) s += *(const h8*)(Tb + j * SLOT + ch[l + j]);
      m = __builtin_elementwise_max(m, s);
    }
    h8 r;
#pragma unroll
    for (int i = 0; i < 8; ++i) r[i] = (_Float16)tanh_fast((float)m[i]);
    const int s8 = WI * 13 + oct;
    *(h8*)(convG + ((size_t)s8 * NT + token) * 8) = r;
  }
}

__global__ __launch_bounds__(1024) void k_conv(const int* __restrict__ chars,
                                               const _Float16* __restrict__ T3,
                                               _Float16* __restrict__ convG) {
  __shared__ __align__(16) _Float16 Ts[5 * SLOT];   // 99,840 B max (w=5)
  const int b = blockIdx.x;
  int wi, b0, TC;
  if (b < 84)       { wi = 3; b0 = 0;   TC = 305; }
  else if (b < 156) { wi = 2; b0 = 84;  TC = 356; }
  else if (b < 214) { wi = 1; b0 = 156; TC = 442; }
  else              { wi = 0; b0 = 214; TC = 610; }
  const int W = wi + 2;
  const int SB = (wi == 0) ? 0 : (wi == 1) ? 2 : (wi == 2) ? 5 : 9;
  const int t0 = (b - b0) * TC;

  // stage T3 slots [SB, SB+W): contiguous, coalesced, conflict-free
  const _Float16* src = T3 + (size_t)SB * SLOT;
  const int nchunk = W * (SLOT / 8);
  for (int r = threadIdx.x; r < nchunk; r += 1024)
    *(h8*)(Ts + r * 8) = *(const h8*)(src + r * 8);
  __syncthreads();

  switch (wi) {
    case 0: conv_block<0>(chars, Ts, convG, t0, TC); break;
    case 1: conv_block<1>(chars, Ts, convG, t0, TC); break;
    case 2: conv_block<2>(chars, Ts, convG, t0, TC); break;
    default: conv_block<3>(chars, Ts, convG, t0, TC); break;
  }
}

// ================= head kernel: MFMA proj + 2 highway layers =================
// 64 tokens/block, 512 threads (8 waves); wave = n-tile (hc = wave*16+m16).
// A-frags read DIRECTLY from convG (4x 256B coalesced runs per wave, L3-resident).
// A-frag (16x16x32 f16): A[m=lane&15][k=quad*8+j]; D: row=quad*4+reg, col=lane&15.
__global__ __launch_bounds__(512) void k_head(
    const _Float16* __restrict__ convG,
    const _Float16* __restrict__ wprojP,
    const _Float16* __restrict__ hw,
    const float* __restrict__ tb0, const float* __restrict__ tb1,
    const float* __restrict__ gb0, const float* __restrict__ gb1,
    float* __restrict__ out) {
  __shared__ __align__(16) _Float16 xA[16 * 512];   // 16,384 B: [k>>3][64 rows][8]

  const int tid = threadIdx.x;
  const int wave = tid >> 6, lane = tid & 63;
  const int m16 = lane & 15, quad = lane >> 4;
  const int tok0 = blockIdx.x * TOKB;
  const f32x4 zero = {0.f, 0.f, 0.f, 0.f};

  // ---- projection GEMM: xp = conv @ wprojP^T, K=416; wave = n-tile ----
  const int hc = wave * 16 + m16;
  f32x4 xp[4];
#pragma unroll
  for (int mt = 0; mt < 4; ++mt) xp[mt] = zero;

  for (int ks = 0; ks < 13; ++ks) {
    const int s8 = ks * 4 + quad;
    h8 b = *(const h8*)(wprojP + (size_t)hc * KP + s8 * 8);
    const _Float16* Ag = convG + ((size_t)s8 * NT + tok0) * 8;
#pragma unroll
    for (int mt = 0; mt < 4; ++mt) {
      h8 a = *(const h8*)(Ag + (mt * 16 + m16) * 8);
      xp[mt] = __builtin_amdgcn_mfma_f32_16x16x32_f16(a, b, xp[mt], 0, 0, 0);
    }
  }

#pragma unroll
  for (int mt = 0; mt < 4; ++mt)
#pragma unroll
    for (int r = 0; r < 4; ++r)
      xA[(hc >> 3) * 512 + (mt * 16 + quad * 4 + r) * 8 + (hc & 7)] =
          (_Float16)xp[mt][r];
  __syncthreads();

#pragma unroll
  for (int layer = 0; layer < 2; ++layer) {
    const _Float16* tw = hw + (layer ? 2 : 0) * HID * HID;
    const _Float16* gw = hw + (layer ? 3 : 1) * HID * HID;
    const float* tbv = layer ? tb1 : tb0;
    const float* gbv = layer ? gb1 : gb0;
    float bt = tbv[hc], bg = gbv[hc];

    f32x4 at[4], ag[4];
#pragma unroll
    for (int mt = 0; mt < 4; ++mt) { at[mt] = zero; ag[mt] = zero; }

#pragma unroll
    for (int ks = 0; ks < 4; ++ks) {
      const int ko = ks * 32 + quad * 8;
      h8 btw = *(const h8*)(tw + (size_t)hc * HID + ko);
      h8 bgw = *(const h8*)(gw + (size_t)hc * HID + ko);
#pragma unroll
      for (int mt = 0; mt < 4; ++mt) {
        h8 a = *(const h8*)(xA + (ks * 4 + quad) * 512 + (mt * 16 + m16) * 8);
        at[mt] = __builtin_amdgcn_mfma_f32_16x16x32_f16(a, btw, at[mt], 0, 0, 0);
        ag[mt] = __builtin_amdgcn_mfma_f32_16x16x32_f16(a, bgw, ag[mt], 0, 0, 0);
      }
    }
    __syncthreads();

#pragma unroll
    for (int mt = 0; mt < 4; ++mt)
#pragma unroll
      for (int r = 0; r < 4; ++r) {
        float g = 1.f / (1.f + __builtin_amdgcn_exp2f(
                             -(ag[mt][r] + bg) * 1.442695041f));
        float tt = fmaxf(at[mt][r] + bt, 0.f);
        float xn = g * tt + (1.f - g) * xp[mt][r];
        xp[mt][r] = xn;
        int row = mt * 16 + quad * 4 + r;
        if (layer == 0)
          xA[(hc >> 3) * 512 + row * 8 + (hc & 7)] = (_Float16)xn;
        else
          out[(size_t)(tok0 + row) * HID + hc] = xn;
      }
    if (layer == 0) __syncthreads();
  }
}

// ================= fallback fused kernel (round-9 structure, T3 layout) =================
template<int WI>
__device__ __forceinline__ void conv_g(const _Float16* __restrict__ T3,
                                       const int* __restrict__ ch,
                                       _Float16* __restrict__ convA,
                                       int lane, int o) {
  constexpr int W = WI + 2, L = 15 - WI;
  constexpr int SB = (WI == 0) ? 0 : (WI == 1) ? 2 : (WI == 2) ? 5 : 9;
  const _Float16* Tb = T3 + (size_t)SB * SLOT + o * 8;
  h8 m;
  {
    h8 s = *(const h8*)(Tb + ch[0]);
#pragma unroll
    for (int j = 1; j < W; ++j) s += *(const h8*)(Tb + j * SLOT + ch[j]);
    m = s;
  }
#pragma unroll
  for (int l = 1; l < L; ++l) {
    h8 s = *(const h8*)(Tb + ch[l]);
#pragma unroll
    for (int j = 1; j < W; ++j) s += *(const h8*)(Tb + j * SLOT + ch[l + j]);
    m = __builtin_elementwise_max(m, s);
  }
  h8 r;
#pragma unroll
  for (int i = 0; i < 8; ++i) r[i] = (_Float16)tanh_fast((float)m[i]);
  const int s8 = WI * 13 + o;
  *(h8*)(convA + (s8 * 64 + lane) * 8) = r;
}

__global__ __launch_bounds__(512) void k_fb(
    const int* __restrict__ chars,
    const _Float16* __restrict__ T3,
    const _Float16* __restrict__ wprojP,
    const _Float16* __restrict__ hw,
    const float* __restrict__ tb0, const float* __restrict__ tb1,
    const float* __restrict__ gb0, const float* __restrict__ gb1,
    float* __restrict__ out) {
  __shared__ __align__(16) char lds[53248];
  _Float16* convA = (_Float16*)lds;
  _Float16* xA    = (_Float16*)lds;

  const int tid = threadIdx.x;
  const int wave = tid >> 6, lane = tid & 63;
  const int m16 = lane & 15, quad = lane >> 4;
  const int tok0 = blockIdx.x * TOKB;
  const f32x4 zero = {0.f, 0.f, 0.f, 0.f};

  int ch[WCH];
  {
    const i32x4* cp = (const i32x4*)(chars + (size_t)(tok0 + lane) * WCH);
#pragma unroll
    for (int q = 0; q < 4; ++q) {
      i32x4 v = cp[q];
#pragma unroll
      for (int i = 0; i < 4; ++i) ch[q * 4 + i] = v[i] * 104;
    }
  }

  switch (wave) {
    case 0: for (int o = 0;  o < 5;  ++o) conv_g<3>(T3, ch, convA, lane, o); break;
    case 1: for (int o = 5;  o < 10; ++o) conv_g<3>(T3, ch, convA, lane, o); break;
    case 2: for (int o = 10; o < 13; ++o) conv_g<3>(T3, ch, convA, lane, o);
            for (int o = 0;  o < 2;  ++o) conv_g<2>(T3, ch, convA, lane, o); break;
    case 3: for (int o = 2;  o < 8;  ++o) conv_g<2>(T3, ch, convA, lane, o); break;
    case 4: for (int o = 8;  o < 13; ++o) conv_g<2>(T3, ch, convA, lane, o);
            conv_g<0>(T3, ch, convA, lane, 0); break;
    case 5: for (int o = 0;  o < 7;  ++o) conv_g<1>(T3, ch, convA, lane, o); break;
    case 6: for (int o = 7;  o < 13; ++o) conv_g<1>(T3, ch, convA, lane, o);
            conv_g<0>(T3, ch, convA, lane, 1); break;
    default: for (int o = 2; o < 13; ++o) conv_g<0>(T3, ch, convA, lane, o); break;
  }
  __syncthreads();

  const int hc = wave * 16 + m16;
  f32x4 xp[4];
#pragma unroll
  for (int mt = 0; mt < 4; ++mt) xp[mt] = zero;
  for (int ks = 0; ks < 13; ++ks) {
    const int s8 = ks * 4 + quad;
    h8 b = *(const h8*)(wprojP + (size_t)hc * KP + s8 * 8);
#pragma unroll
    for (int mt = 0; mt < 4; ++mt) {
      h8 a = *(const h8*)(convA + (s8 * 64 + mt * 16 + m16) * 8);
      xp[mt] = __builtin_amdgcn_mfma_f32_16x16x32_f16(a, b, xp[mt], 0, 0, 0);
    }
  }
  __syncthreads();
#pragma unroll
  for (int mt = 0; mt < 4; ++mt)
#pragma unroll
    for (int r = 0; r < 4; ++r)
      xA[(hc >> 3) * 512 + (mt * 16 + quad * 4 + r) * 8 + (hc & 7)] =
          (_Float16)xp[mt][r];
  __syncthreads();
#pragma unroll
  for (int layer = 0; layer < 2; ++layer) {
    const _Float16* tw = hw + (layer ? 2 : 0) * HID * HID;
    const _Float16* gw = hw + (layer ? 3 : 1) * HID * HID;
    const float* tbv = layer ? tb1 : tb0;
    const float* gbv = layer ? gb1 : gb0;
    float bt = tbv[hc], bg = gbv[hc];
    f32x4 at[4], ag[4];
#pragma unroll
    for (int mt = 0; mt < 4; ++mt) { at[mt] = zero; ag[mt] = zero; }
#pragma unroll
    for (int ks = 0; ks < 4; ++ks) {
      const int ko = ks * 32 + quad * 8;
      h8 btw = *(const h8*)(tw + (size_t)hc * HID + ko);
      h8 bgw = *(const h8*)(gw + (size_t)hc * HID + ko);
#pragma unroll
      for (int mt = 0; mt < 4; ++mt) {
        h8 a = *(const h8*)(xA + (ks * 4 + quad) * 512 + (mt * 16 + m16) * 8);
        at[mt] = __builtin_amdgcn_mfma_f32_16x16x32_f16(a, btw, at[mt], 0, 0, 0);
        ag[mt] = __builtin_amdgcn_mfma_f32_16x16x32_f16(a, bgw, ag[mt], 0, 0, 0);
      }
    }
    __syncthreads();
#pragma unroll
    for (int mt = 0; mt < 4; ++mt)
#pragma unroll
      for (int r = 0; r < 4; ++r) {
        float g = 1.f / (1.f + __builtin_amdgcn_exp2f(
                             -(ag[mt][r] + bg) * 1.442695041f));
        float tt = fmaxf(at[mt][r] + bt, 0.f);
        float xn = g * tt + (1.f - g) * xp[mt][r];
        xp[mt][r] = xn;
        int row = mt * 16 + quad * 4 + r;
        if (layer == 0)
          xA[(hc >> 3) * 512 + row * 8 + (hc & 7)] = (_Float16)xn;
        else
          out[(size_t)(tok0 + row) * HID + hc] = xn;
      }
    if (layer == 0) __syncthreads();
  }
}

extern "C" void kernel_launch(void* const* d_in, const int* in_sizes, int n_in,
                              void* d_out, int out_size, void* d_ws, size_t ws_size,
                              hipStream_t stream) {
  (void)in_sizes; (void)n_in; (void)out_size;
  const int* chars = (const int*)d_in[0];
  const float* cv  = (const float*)d_in[1];
  const float* f2  = (const float*)d_in[2];
  const float* f3  = (const float*)d_in[3];
  const float* f4  = (const float*)d_in[4];
  const float* f5  = (const float*)d_in[5];
  const float* wpj = (const float*)d_in[6];
  const float* tw0 = (const float*)d_in[7];
  const float* tb0 = (const float*)d_in[8];
  const float* tw1 = (const float*)d_in[9];
  const float* tb1 = (const float*)d_in[10];
  const float* gw0 = (const float*)d_in[11];
  const float* gb0 = (const float*)d_in[12];
  const float* gw1 = (const float*)d_in[13];
  const float* gb1 = (const float*)d_in[14];
  float* out = (float*)d_out;

  char* ws = (char*)d_ws;
  _Float16* T3     = (_Float16*)ws;                       // 279,552 B
  _Float16* wprojP = (_Float16*)(ws + 279552);            // 106,496 B
  _Float16* hw     = (_Float16*)(ws + 386048);            // 131,072 B
  _Float16* convG  = (_Float16*)(ws + 517120);            // 21,299,200 B

  k_prep<<<488, 256, 0, stream>>>(cv, f2, f3, f4, f5, wpj, tw0, gw0, tw1, gw1,
                                  T3, wprojP, hw);
  if (ws_size >= (size_t)21816320) {
    k_conv<<<256, 1024, 0, stream>>>(chars, T3, convG);
    k_head<<<NT / TOKB, 512, 0, stream>>>(convG, wprojP, hw,
                                          tb0, tb1, gb0, gb1, out);
  } else {
    k_fb<<<NT / TOKB, 512, 0, stream>>>(chars, T3, wprojP, hw,
                                        tb0, tb1, gb0, gb1, out);
  }
}